// Round 1
// baseline (67.169 us; speedup 1.0000x reference)
//
#include <hip/hip_runtime.h>

// Problem constants (from reference setup_inputs)
#define B_ 16
#define H_ 100
#define W_ 100
#define C_ 256
#define R_ 128
#define P_ 7
#define C4_ (C_ / 4)          // 64 float4 per (b,r,py,px) position

// out[b, r, py, px, c] = bilinear sample of fm[b] at TF2 half-pixel-center
// coords within the integer crop (x, y, h, w) = rois[b, r].
__global__ void roi_bilinear_kernel(const float* __restrict__ fm,
                                    const int* __restrict__ rois,
                                    float* __restrict__ out,
                                    int n4) {
    int idx = blockIdx.x * blockDim.x + threadIdx.x;
    const int stride = gridDim.x * blockDim.x;

    for (; idx < n4; idx += stride) {
        // idx = (((b*R + r)*P + py)*P + px) * C4 + c4
        const int c4  = idx & (C4_ - 1);     // 64 lanes == one position's channels
        const int pos = idx >> 6;
        const int px  = pos % P_;
        const int t1  = pos / P_;
        const int py  = t1 % P_;
        const int t2  = t1 / P_;
        const int r   = t2 & (R_ - 1);
        const int b   = t2 >> 7;

        // Wave-uniform ROI fetch (same address for all 64 lanes -> broadcast)
        const int* roi = rois + ((b * R_ + r) << 2);
        const int x = roi[0];
        const int y = roi[1];
        const int h = roi[2];
        const int w = roi[3];

        // y-axis source coord: src = ((py+0.5)/P)*h - 0.5, clip [0, h-1]
        const float hf = (float)h;
        float sy = ((py + 0.5f) / (float)P_) * hf - 0.5f;
        sy = fminf(fmaxf(sy, 0.0f), hf - 1.0f);
        int   y0 = (int)floorf(sy);
        const float fy = sy - (float)y0;
        y0 += y;
        const int y1 = min(y0 + 1, y + h - 1);

        // x-axis
        const float wf = (float)w;
        float sx = ((px + 0.5f) / (float)P_) * wf - 0.5f;
        sx = fminf(fmaxf(sx, 0.0f), wf - 1.0f);
        int   x0 = (int)floorf(sx);
        const float fx = sx - (float)x0;
        x0 += x;
        const int x1 = min(x0 + 1, x + w - 1);

        // Coalesced float4 gathers: 64 consecutive lanes cover 256 channels
        const float4* base = (const float4*)fm + (size_t)b * (H_ * W_ * C4_);
        const float4 va = base[(y0 * W_ + x0) * C4_ + c4];
        const float4 vb = base[(y0 * W_ + x1) * C4_ + c4];
        const float4 vc = base[(y1 * W_ + x0) * C4_ + c4];
        const float4 vd = base[(y1 * W_ + x1) * C4_ + c4];

        float4 o;
        {
            const float top_x = va.x + (vb.x - va.x) * fx;
            const float bot_x = vc.x + (vd.x - vc.x) * fx;
            o.x = top_x + (bot_x - top_x) * fy;
            const float top_y = va.y + (vb.y - va.y) * fx;
            const float bot_y = vc.y + (vd.y - vc.y) * fx;
            o.y = top_y + (bot_y - top_y) * fy;
            const float top_z = va.z + (vb.z - va.z) * fx;
            const float bot_z = vc.z + (vd.z - vc.z) * fx;
            o.z = top_z + (bot_z - top_z) * fy;
            const float top_w = va.w + (vb.w - va.w) * fx;
            const float bot_w = vc.w + (vd.w - vc.w) * fx;
            o.w = top_w + (bot_w - top_w) * fy;
        }

        ((float4*)out)[idx] = o;
    }
}

extern "C" void kernel_launch(void* const* d_in, const int* in_sizes, int n_in,
                              void* d_out, int out_size, void* d_ws, size_t ws_size,
                              hipStream_t stream) {
    const float* fm   = (const float*)d_in[0];   // [B, H, W, C] f32
    const int*   rois = (const int*)d_in[1];     // [B, R, 4]   i32
    // d_in[2] = pool_size (7), hard-coded above.

    const int n4 = out_size / 4;                 // float4 elements
    const int block = 256;
    int grid = (n4 + block - 1) / block;
    if (grid > 2048) grid = 2048;                // grid-stride beyond this

    roi_bilinear_kernel<<<grid, block, 0, stream>>>(fm, rois, (float*)d_out, n4);
}

// Round 3
// 37.564 us; speedup vs baseline: 1.7881x; 1.7881x over previous
//
#include <hip/hip_runtime.h>

// Problem constants (from reference setup_inputs)
#define B_ 16
#define H_ 100
#define W_ 100
#define C_ 256
#define R_ 128
#define P_ 7
#define C4_ (C_ / 4)          // 64 float4 per (b,r,py,px) position

#define NPOS_ (B_ * R_ * P_ * P_)       // 100352 wave-positions
#define NWG_  (NPOS_ / 4)               // 25088 blocks of 256 (4 waves each)
#define CPX_  (NWG_ / 8)                // 3136 blocks per XCD (= 2 images)

typedef float f32x4 __attribute__((ext_vector_type(4)));  // clang vector: ok for nontemporal builtin

// out[b, r, py, px, c] = bilinear sample of fm[b] at TF2 half-pixel-center
// coords within the integer crop (x, y, h, w) = rois[b, r].
__global__ void __launch_bounds__(256) roi_bilinear_kernel(
        const float* __restrict__ fm,
        const int* __restrict__ rois,
        float* __restrict__ out) {
    // Bijective XCD swizzle: NWG_ % 8 == 0, so XCD k gets the contiguous
    // block range [k*CPX_, (k+1)*CPX_) == images b = 2k, 2k+1. Keeps the
    // 2x2-corner re-reads of one image inside one XCD's private L2.
    const int bid = (blockIdx.x & 7) * CPX_ + (blockIdx.x >> 3);
    const int idx = bid * 256 + threadIdx.x;

    // idx = (((b*R + r)*P + py)*P + px) * C4 + c4
    const int c4  = idx & (C4_ - 1);     // 64 lanes == one position's channels
    const int pos = idx >> 6;
    const int px  = pos % P_;
    const int t1  = pos / P_;
    const int py  = t1 % P_;
    const int t2  = t1 / P_;
    const int r   = t2 & (R_ - 1);
    const int b   = t2 >> 7;

    // Wave-uniform ROI fetch (same address for all 64 lanes -> broadcast)
    const int* roi = rois + ((b * R_ + r) << 2);
    const int x = roi[0];
    const int y = roi[1];
    const int h = roi[2];
    const int w = roi[3];

    // y-axis source coord: src = ((py+0.5)/P)*h - 0.5, clip [0, h-1]
    const float hf = (float)h;
    float sy = ((py + 0.5f) / (float)P_) * hf - 0.5f;
    sy = fminf(fmaxf(sy, 0.0f), hf - 1.0f);
    int   y0 = (int)floorf(sy);
    const float fy = sy - (float)y0;
    y0 += y;
    const int y1 = min(y0 + 1, y + h - 1);

    // x-axis
    const float wf = (float)w;
    float sx = ((px + 0.5f) / (float)P_) * wf - 0.5f;
    sx = fminf(fmaxf(sx, 0.0f), wf - 1.0f);
    int   x0 = (int)floorf(sx);
    const float fx = sx - (float)x0;
    x0 += x;
    const int x1 = min(x0 + 1, x + w - 1);

    // Coalesced float4 gathers: 64 consecutive lanes cover 256 channels
    const f32x4* base = (const f32x4*)fm + (size_t)b * (H_ * W_ * C4_);
    const f32x4 va = base[(y0 * W_ + x0) * C4_ + c4];
    const f32x4 vb = base[(y0 * W_ + x1) * C4_ + c4];
    const f32x4 vc = base[(y1 * W_ + x0) * C4_ + c4];
    const f32x4 vd = base[(y1 * W_ + x1) * C4_ + c4];

    const f32x4 top = va + (vb - va) * fx;
    const f32x4 bot = vc + (vd - vc) * fx;
    const f32x4 o   = top + (bot - top) * fy;

    // Streaming store: out is write-once, never re-read -> don't evict
    // feature-map lines from L2 for it.
    __builtin_nontemporal_store(o, (f32x4*)out + idx);
}

extern "C" void kernel_launch(void* const* d_in, const int* in_sizes, int n_in,
                              void* d_out, int out_size, void* d_ws, size_t ws_size,
                              hipStream_t stream) {
    const float* fm   = (const float*)d_in[0];   // [B, H, W, C] f32
    const int*   rois = (const int*)d_in[1];     // [B, R, 4]   i32
    // d_in[2] = pool_size (7), hard-coded above.

    roi_bilinear_kernel<<<NWG_, 256, 0, stream>>>(fm, rois, (float*)d_out);
}